// Round 4
// baseline (201.525 us; speedup 1.0000x reference)
//
#include <hip/hip_runtime.h>

typedef __attribute__((ext_vector_type(8))) short          short8;   // 8 bf16 for MFMA A/B
typedef __attribute__((ext_vector_type(4))) float          f32x4;    // MFMA C/D + vec io
typedef __attribute__((ext_vector_type(8))) unsigned short ushort8;  // 8 bf16 table load

#define ALPHA 0.2f

__device__ __forceinline__ unsigned short f2bf(float f) {
    union { float f; unsigned int u; } x; x.f = f;
    unsigned int u = x.u;
    u += 0x7fffu + ((u >> 16) & 1u);   // RNE
    return (unsigned short)(u >> 16);
}
__device__ __forceinline__ float bf2f(unsigned short u) {
    union { unsigned int i; float f; } x; x.i = ((unsigned int)u) << 16;
    return x.f;
}

// ---------------------------------------------------------------------------
// Kernel 1: fused fold (PW = P @ W_block) + fragment build, one thread per
// bf16 frag element. All operands (P*, W: 256 KB) are L2-resident.
// Frag layout per type: frag[kk][ct][lane][j], k = kk*32 + (lane>>4)*8 + j,
// col c = ct*16 + (lane&15). disease: C=128 (PW0|PW1), gene/chem: C=64.
// ---------------------------------------------------------------------------
__global__ __launch_bounds__(256)
void make_frags(const float* __restrict__ Pd, const float* __restrict__ Pg,
                const float* __restrict__ Pc, const float* __restrict__ W,
                unsigned short* __restrict__ fd, unsigned short* __restrict__ fg,
                unsigned short* __restrict__ fc) {
    int t = blockIdx.x * 256 + threadIdx.x;        // 0..65535
    int local, NCT, mbase; unsigned short* dst;
    if (t < 32768)      { local = t;         NCT = 8; dst = fd; mbase = 0; }
    else if (t < 49152) { local = t - 32768; NCT = 4; dst = fg; mbase = 2; }
    else                { local = t - 49152; NCT = 4; dst = fc; mbase = 3; }
    int j    = local & 7;
    int lane = (local >> 3) & 63;
    int ct   = (local >> 9) & (NCT - 1);
    int kk   = local >> (9 + (NCT == 8 ? 3 : 2));
    int k = kk * 32 + ((lane >> 4) << 3) + j;      // K index 0..255
    int c = ct * 16 + (lane & 15);                 // output col
    int m, cc; const float* P;
    if (NCT == 8) { m = (c < 64) ? 0 : 1; cc = c & 63; P = Pd; }
    else          { m = mbase;            cc = c;      P = (mbase == 2) ? Pg : Pc; }
    // PW[m][k][cc] = sum_q P[k][q] * W[m*64+q][cc]
    float acc = 0.f;
    #pragma unroll 8
    for (int q = 0; q < 64; ++q)
        acc += P[k * 64 + q] * W[(m * 64 + q) * 64 + cc];
    dst[local] = f2bf(acc);
}

// ---------------------------------------------------------------------------
// Kernel 2: fused node projection GEMMs  g = feats[N,256] @ PW  (bf16 MFMA),
// g stored in bf16. 512-thread block = 8 waves; TPW tiles per wave.
// Frag staging: exactly NCT*4096 ushorts (64 KiB for NCT=8, 32 KiB for NCT=4).
// ---------------------------------------------------------------------------
#define TPW 2

template <int NCT>
__device__ __forceinline__
void proj_body(const float* __restrict__ feats,
               const unsigned short* __restrict__ bfrag,
               unsigned short* __restrict__ g, int ntiles, int blk,
               unsigned short* blds) {
    const int t = threadIdx.x;
    #pragma unroll
    for (int i = 0; i < NCT; ++i) {                // NCT*512*8 ushorts = frag size
        int off = (i * 512 + t) * 8;               // ushort index, 16B chunks
        *(int4*)&blds[off] = *(const int4*)&bfrag[off];
    }
    __syncthreads();

    const int wid = t >> 6, lane = t & 63;
    const int C = NCT * 16;

    #pragma unroll
    for (int it = 0; it < TPW; ++it) {
        const int tile = (blk * 8 + wid) * TPW + it;
        if (tile >= ntiles) return;

        const int row = tile * 16 + (lane & 15);
        const float* arow = feats + (size_t)row * 256 + ((lane >> 4) * 8);

        f32x4 acc[NCT];
        #pragma unroll
        for (int ct = 0; ct < NCT; ++ct) acc[ct] = (f32x4){0.f, 0.f, 0.f, 0.f};

        #pragma unroll
        for (int kk = 0; kk < 8; ++kk) {
            // single-use stream: nontemporal, keep L2/L3 for the g tables
            f32x4 v0 = __builtin_nontemporal_load((const f32x4*)(arow + kk * 32));
            f32x4 v1 = __builtin_nontemporal_load((const f32x4*)(arow + kk * 32 + 4));
            short8 a;
            a[0] = (short)f2bf(v0[0]); a[1] = (short)f2bf(v0[1]);
            a[2] = (short)f2bf(v0[2]); a[3] = (short)f2bf(v0[3]);
            a[4] = (short)f2bf(v1[0]); a[5] = (short)f2bf(v1[1]);
            a[6] = (short)f2bf(v1[2]); a[7] = (short)f2bf(v1[3]);
            #pragma unroll
            for (int ct = 0; ct < NCT; ++ct) {
                short8 b = *(const short8*)&blds[((kk * NCT + ct) * 64 + lane) * 8];
                acc[ct] = __builtin_amdgcn_mfma_f32_16x16x32_bf16(a, b, acc[ct], 0, 0, 0);
            }
        }

        // C/D layout: col = lane&15, row = (lane>>4)*4 + j   [m89 verified]
        const int rbase = tile * 16 + (lane >> 4) * 4;
        const int cbase = lane & 15;
        #pragma unroll
        for (int ct = 0; ct < NCT; ++ct) {
            #pragma unroll
            for (int j = 0; j < 4; ++j)
                g[(size_t)(rbase + j) * C + ct * 16 + cbase] = f2bf(acc[ct][j]);
        }
    }
}

__global__ __launch_bounds__(512)
void proj_all(const float* __restrict__ featd, const float* __restrict__ featg,
              const float* __restrict__ featc,
              const unsigned short* __restrict__ fragd,
              const unsigned short* __restrict__ fragg,
              const unsigned short* __restrict__ fragc,
              unsigned short* __restrict__ g_d, unsigned short* __restrict__ g_g,
              unsigned short* __restrict__ g_c,
              int nbd, int nbg, int td, int tg, int tc) {
    __shared__ unsigned short blds[32768];         // 64 KiB (max: NCT=8)
    int b = blockIdx.x;
    if (b < nbd)            proj_body<8>(featd, fragd, g_d, td, b,             blds);
    else if (b < nbd + nbg) proj_body<4>(featg, fragg, g_g, tg, b - nbd,       blds);
    else                    proj_body<4>(featc, fragc, g_c, tc, b - nbd - nbg, blds);
}

// ---------------------------------------------------------------------------
// Kernel 3: per-edge gather + add + LeakyReLU, 2 edges per thread for MLP.
// 8 lanes per edge; each lane: 4× 16B bf16 loads (cached) -> 32B fp32 out (NT).
// g_d rows are 128 bf16 wide (d0-part | d1-part).
// ---------------------------------------------------------------------------
__global__ __launch_bounds__(256)
void gather_kernel(const unsigned short* __restrict__ g_d,
                   const unsigned short* __restrict__ g_g,
                   const unsigned short* __restrict__ g_c,
                   const int* __restrict__ i0, const int* __restrict__ i1,
                   const int* __restrict__ ig, const int* __restrict__ ic,
                   float* __restrict__ out, int E, int Eh) {
    int tid = blockIdx.x * 256 + threadIdx.x;
    int e0 = tid >> 3;
    if (e0 >= Eh) return;
    int q = tid & 3;          // 16B slot within 64B half... (see below)
    q = tid & 7;              // 8 slots of 8 bf16
    int e1 = e0 + Eh;
    bool has1 = e1 < E;

    // issue all idx loads first (single-use: nontemporal)
    int a0  = __builtin_nontemporal_load(i0 + e0);
    int b0  = __builtin_nontemporal_load(i1 + e0);
    int gi0 = __builtin_nontemporal_load(ig + e0);
    int ci0 = __builtin_nontemporal_load(ic + e0);
    int a1 = 0, b1 = 0, gi1 = 0, ci1 = 0;
    if (has1) {
        a1  = __builtin_nontemporal_load(i0 + e1);
        b1  = __builtin_nontemporal_load(i1 + e1);
        gi1 = __builtin_nontemporal_load(ig + e1);
        ci1 = __builtin_nontemporal_load(ic + e1);
    }

    // issue all table loads (cached; tables are L2/L3-resident)
    ushort8 v0 = *(const ushort8*)(g_d + (size_t)a0  * 128 + q * 8);
    ushort8 v1 = *(const ushort8*)(g_d + (size_t)b0  * 128 + 64 + q * 8);
    ushort8 v2 = *(const ushort8*)(g_g + (size_t)gi0 * 64 + q * 8);
    ushort8 v3 = *(const ushort8*)(g_c + (size_t)ci0 * 64 + q * 8);
    ushort8 w0, w1, w2, w3;
    if (has1) {
        w0 = *(const ushort8*)(g_d + (size_t)a1  * 128 + q * 8);
        w1 = *(const ushort8*)(g_d + (size_t)b1  * 128 + 64 + q * 8);
        w2 = *(const ushort8*)(g_g + (size_t)gi1 * 64 + q * 8);
        w3 = *(const ushort8*)(g_c + (size_t)ci1 * 64 + q * 8);
    }

    f32x4 r0, r1;
    #pragma unroll
    for (int j = 0; j < 4; ++j) {
        float s = bf2f(v0[j]) + bf2f(v1[j]) + bf2f(v2[j]) + bf2f(v3[j]);
        r0[j] = s >= 0.f ? s : s * ALPHA;
        float u = bf2f(v0[j + 4]) + bf2f(v1[j + 4]) + bf2f(v2[j + 4]) + bf2f(v3[j + 4]);
        r1[j] = u >= 0.f ? u : u * ALPHA;
    }
    float* o0 = out + (size_t)e0 * 64 + q * 8;
    __builtin_nontemporal_store(r0, (f32x4*)o0);
    __builtin_nontemporal_store(r1, (f32x4*)(o0 + 4));

    if (has1) {
        #pragma unroll
        for (int j = 0; j < 4; ++j) {
            float s = bf2f(w0[j]) + bf2f(w1[j]) + bf2f(w2[j]) + bf2f(w3[j]);
            r0[j] = s >= 0.f ? s : s * ALPHA;
            float u = bf2f(w0[j + 4]) + bf2f(w1[j + 4]) + bf2f(w2[j + 4]) + bf2f(w3[j + 4]);
            r1[j] = u >= 0.f ? u : u * ALPHA;
        }
        float* o1 = out + (size_t)e1 * 64 + q * 8;
        __builtin_nontemporal_store(r0, (f32x4*)o1);
        __builtin_nontemporal_store(r1, (f32x4*)(o1 + 4));
    }
}

// ---------------------------------------------------------------------------
extern "C" void kernel_launch(void* const* d_in, const int* in_sizes, int n_in,
                              void* d_out, int out_size, void* d_ws, size_t ws_size,
                              hipStream_t stream) {
    const float* feats_d = (const float*)d_in[0];
    const float* feats_g = (const float*)d_in[1];
    const float* feats_c = (const float*)d_in[2];
    // d_in[3] species feats: dead code in reference
    const float* Pd = (const float*)d_in[4];
    const float* Pg = (const float*)d_in[5];
    const float* Pc = (const float*)d_in[6];
    // d_in[7] P_species: dead code
    const float* W  = (const float*)d_in[8];
    const int* i0 = (const int*)d_in[9];
    const int* i1 = (const int*)d_in[10];
    const int* ig = (const int*)d_in[11];
    const int* ic = (const int*)d_in[12];
    float* out = (float*)d_out;

    const int N_D = in_sizes[0] / 256;
    const int N_G = in_sizes[1] / 256;
    const int N_C = in_sizes[2] / 256;
    const int E   = in_sizes[9];

    char* ws = (char*)d_ws;
    unsigned short* fd  = (unsigned short*)ws;                 // 64 KiB
    unsigned short* fg  = (unsigned short*)(ws + 65536);       // 32 KiB
    unsigned short* fc  = (unsigned short*)(ws + 98304);       // 32 KiB
    unsigned short* g_d = (unsigned short*)(ws + 131072);      // N_D*128 bf16
    unsigned short* g_g = g_d + (size_t)N_D * 128;             // N_G*64
    unsigned short* g_c = g_g + (size_t)N_G * 64;              // N_C*64

    make_frags<<<256, 256, 0, stream>>>(Pd, Pg, Pc, W, fd, fg, fc);

    int td = N_D / 16, tg = N_G / 16, tc = N_C / 16;
    int nbd = (td + 8 * TPW - 1) / (8 * TPW);
    int nbg = (tg + 8 * TPW - 1) / (8 * TPW);
    int nbc = (tc + 8 * TPW - 1) / (8 * TPW);
    proj_all<<<nbd + nbg + nbc, 512, 0, stream>>>(
        feats_d, feats_g, feats_c, fd, fg, fc, g_d, g_g, g_c,
        nbd, nbg, td, tg, tc);

    int Eh = (E + 1) / 2;
    long long nthreads = (long long)Eh * 8;
    gather_kernel<<<(int)((nthreads + 255) / 256), 256, 0, stream>>>(
        g_d, g_g, g_c, i0, i1, ig, ic, out, E, Eh);
}

// Round 5
// 166.326 us; speedup vs baseline: 1.2116x; 1.2116x over previous
//
#include <hip/hip_runtime.h>

typedef __attribute__((ext_vector_type(8))) short          short8;   // 8 bf16 for MFMA A/B
typedef __attribute__((ext_vector_type(4))) float          f32x4;    // MFMA C/D + vec io
typedef __attribute__((ext_vector_type(8))) unsigned short ushort8;  // 8 bf16 table load

#define ALPHA 0.2f

__device__ __forceinline__ unsigned short f2bf(float f) {
    union { float f; unsigned int u; } x; x.f = f;
    unsigned int u = x.u;
    u += 0x7fffu + ((u >> 16) & 1u);   // RNE
    return (unsigned short)(u >> 16);
}
__device__ __forceinline__ float bf2f(unsigned short u) {
    union { unsigned int i; float f; } x; x.i = ((unsigned int)u) << 16;
    return x.f;
}

// ---------------------------------------------------------------------------
// Kernel 1: fused fold (PW = P @ W_block) + fragment build, one thread per
// bf16 frag element. All operands (P*, W: 256 KB) are L2-resident.
// Frag layout per type: frag[kk][ct][lane][j], k = kk*32 + (lane>>4)*8 + j,
// col c = ct*16 + (lane&15). disease: C=128 (PW0|PW1), gene/chem: C=64.
// ---------------------------------------------------------------------------
__global__ __launch_bounds__(256)
void make_frags(const float* __restrict__ Pd, const float* __restrict__ Pg,
                const float* __restrict__ Pc, const float* __restrict__ W,
                unsigned short* __restrict__ fd, unsigned short* __restrict__ fg,
                unsigned short* __restrict__ fc) {
    int t = blockIdx.x * 256 + threadIdx.x;        // 0..65535
    int local, NCT, mbase; unsigned short* dst;
    if (t < 32768)      { local = t;         NCT = 8; dst = fd; mbase = 0; }
    else if (t < 49152) { local = t - 32768; NCT = 4; dst = fg; mbase = 2; }
    else                { local = t - 49152; NCT = 4; dst = fc; mbase = 3; }
    int j    = local & 7;
    int lane = (local >> 3) & 63;
    int ct   = (local >> 9) & (NCT - 1);
    int kk   = local >> (9 + (NCT == 8 ? 3 : 2));
    int k = kk * 32 + ((lane >> 4) << 3) + j;      // K index 0..255
    int c = ct * 16 + (lane & 15);                 // output col
    int m, cc; const float* P;
    if (NCT == 8) { m = (c < 64) ? 0 : 1; cc = c & 63; P = Pd; }
    else          { m = mbase;            cc = c;      P = (mbase == 2) ? Pg : Pc; }
    // PW[m][k][cc] = sum_q P[k][q] * W[m*64+q][cc]
    float acc = 0.f;
    #pragma unroll 8
    for (int q = 0; q < 64; ++q)
        acc += P[k * 64 + q] * W[(m * 64 + q) * 64 + cc];
    dst[local] = f2bf(acc);
}

// ---------------------------------------------------------------------------
// Kernel 2: fused node projection GEMMs  g = feats[N,256] @ PW  (bf16 MFMA),
// g stored in bf16. One 512-thread block = 8 waves, one 16-row tile per wave.
// Frag staging: exactly NCT*4096 ushorts (64 KiB for NCT=8, 32 KiB for NCT=4).
// ---------------------------------------------------------------------------
template <int NCT>
__device__ __forceinline__
void proj_body(const float* __restrict__ feats,
               const unsigned short* __restrict__ bfrag,
               unsigned short* __restrict__ g, int ntiles, int blk,
               unsigned short* blds) {
    const int t = threadIdx.x;
    #pragma unroll
    for (int i = 0; i < NCT; ++i) {                // NCT*512*8 ushorts = frag size
        int off = (i * 512 + t) * 8;               // ushort index, 16B chunks
        *(int4*)&blds[off] = *(const int4*)&bfrag[off];
    }
    __syncthreads();

    const int wid = t >> 6, lane = t & 63;
    const int C = NCT * 16;
    const int tile = blk * 8 + wid;
    if (tile >= ntiles) return;

    const int row = tile * 16 + (lane & 15);
    const float* arow = feats + (size_t)row * 256 + ((lane >> 4) * 8);

    f32x4 acc[NCT];
    #pragma unroll
    for (int ct = 0; ct < NCT; ++ct) acc[ct] = (f32x4){0.f, 0.f, 0.f, 0.f};

    #pragma unroll
    for (int kk = 0; kk < 8; ++kk) {
        f32x4 v0 = *(const f32x4*)(arow + kk * 32);
        f32x4 v1 = *(const f32x4*)(arow + kk * 32 + 4);
        short8 a;
        a[0] = (short)f2bf(v0[0]); a[1] = (short)f2bf(v0[1]);
        a[2] = (short)f2bf(v0[2]); a[3] = (short)f2bf(v0[3]);
        a[4] = (short)f2bf(v1[0]); a[5] = (short)f2bf(v1[1]);
        a[6] = (short)f2bf(v1[2]); a[7] = (short)f2bf(v1[3]);
        #pragma unroll
        for (int ct = 0; ct < NCT; ++ct) {
            short8 b = *(const short8*)&blds[((kk * NCT + ct) * 64 + lane) * 8];
            acc[ct] = __builtin_amdgcn_mfma_f32_16x16x32_bf16(a, b, acc[ct], 0, 0, 0);
        }
    }

    // C/D layout: col = lane&15, row = (lane>>4)*4 + j   [m89 verified]
    const int rbase = tile * 16 + (lane >> 4) * 4;
    const int cbase = lane & 15;
    #pragma unroll
    for (int ct = 0; ct < NCT; ++ct) {
        #pragma unroll
        for (int j = 0; j < 4; ++j)
            g[(size_t)(rbase + j) * C + ct * 16 + cbase] = f2bf(acc[ct][j]);
    }
}

__global__ __launch_bounds__(512)
void proj_all(const float* __restrict__ featd, const float* __restrict__ featg,
              const float* __restrict__ featc,
              const unsigned short* __restrict__ fragd,
              const unsigned short* __restrict__ fragg,
              const unsigned short* __restrict__ fragc,
              unsigned short* __restrict__ g_d, unsigned short* __restrict__ g_g,
              unsigned short* __restrict__ g_c,
              int nbd, int nbg, int td, int tg, int tc) {
    __shared__ unsigned short blds[32768];         // 64 KiB (max: NCT=8)
    int b = blockIdx.x;
    if (b < nbd)            proj_body<8>(featd, fragd, g_d, td, b,             blds);
    else if (b < nbd + nbg) proj_body<4>(featg, fragg, g_g, tg, b - nbd,       blds);
    else                    proj_body<4>(featc, fragc, g_c, tc, b - nbd - nbg, blds);
}

// ---------------------------------------------------------------------------
// Kernel 3: per-edge gather + add + LeakyReLU.
// 8 lanes per edge; each lane: 4× 16B bf16 loads (cached) -> 32B fp32 out (NT).
// g_d rows are 128 bf16 wide (d0-part | d1-part).
// ---------------------------------------------------------------------------
__global__ __launch_bounds__(256)
void gather_kernel(const unsigned short* __restrict__ g_d,
                   const unsigned short* __restrict__ g_g,
                   const unsigned short* __restrict__ g_c,
                   const int* __restrict__ i0, const int* __restrict__ i1,
                   const int* __restrict__ ig, const int* __restrict__ ic,
                   float* __restrict__ out, int E) {
    int tid = blockIdx.x * 256 + threadIdx.x;
    int e = tid >> 3;
    if (e >= E) return;
    int q = tid & 7;

    int a  = __builtin_nontemporal_load(i0 + e);
    int b  = __builtin_nontemporal_load(i1 + e);
    int gi = __builtin_nontemporal_load(ig + e);
    int ci = __builtin_nontemporal_load(ic + e);

    ushort8 v0 = *(const ushort8*)(g_d + (size_t)a * 128 + q * 8);
    ushort8 v1 = *(const ushort8*)(g_d + (size_t)b * 128 + 64 + q * 8);
    ushort8 v2 = *(const ushort8*)(g_g + (size_t)gi * 64 + q * 8);
    ushort8 v3 = *(const ushort8*)(g_c + (size_t)ci * 64 + q * 8);

    f32x4 r0, r1;
    #pragma unroll
    for (int j = 0; j < 4; ++j) {
        float s = bf2f(v0[j]) + bf2f(v1[j]) + bf2f(v2[j]) + bf2f(v3[j]);
        r0[j] = s >= 0.f ? s : s * ALPHA;
        float u = bf2f(v0[j + 4]) + bf2f(v1[j + 4]) + bf2f(v2[j + 4]) + bf2f(v3[j + 4]);
        r1[j] = u >= 0.f ? u : u * ALPHA;
    }

    // streaming writes: don't evict the L3-resident g tables
    float* o = out + (size_t)e * 64 + q * 8;
    __builtin_nontemporal_store(r0, (f32x4*)o);
    __builtin_nontemporal_store(r1, (f32x4*)(o + 4));
}

// ---------------------------------------------------------------------------
extern "C" void kernel_launch(void* const* d_in, const int* in_sizes, int n_in,
                              void* d_out, int out_size, void* d_ws, size_t ws_size,
                              hipStream_t stream) {
    const float* feats_d = (const float*)d_in[0];
    const float* feats_g = (const float*)d_in[1];
    const float* feats_c = (const float*)d_in[2];
    // d_in[3] species feats: dead code in reference
    const float* Pd = (const float*)d_in[4];
    const float* Pg = (const float*)d_in[5];
    const float* Pc = (const float*)d_in[6];
    // d_in[7] P_species: dead code
    const float* W  = (const float*)d_in[8];
    const int* i0 = (const int*)d_in[9];
    const int* i1 = (const int*)d_in[10];
    const int* ig = (const int*)d_in[11];
    const int* ic = (const int*)d_in[12];
    float* out = (float*)d_out;

    const int N_D = in_sizes[0] / 256;
    const int N_G = in_sizes[1] / 256;
    const int N_C = in_sizes[2] / 256;
    const int E   = in_sizes[9];

    char* ws = (char*)d_ws;
    unsigned short* fd  = (unsigned short*)ws;                 // 64 KiB
    unsigned short* fg  = (unsigned short*)(ws + 65536);       // 32 KiB
    unsigned short* fc  = (unsigned short*)(ws + 98304);       // 32 KiB
    unsigned short* g_d = (unsigned short*)(ws + 131072);      // N_D*128 bf16
    unsigned short* g_g = g_d + (size_t)N_D * 128;             // N_G*64
    unsigned short* g_c = g_g + (size_t)N_G * 64;              // N_C*64

    make_frags<<<256, 256, 0, stream>>>(Pd, Pg, Pc, W, fd, fg, fc);

    int td = N_D / 16, tg = N_G / 16, tc = N_C / 16;
    int nbd = (td + 7) / 8, nbg = (tg + 7) / 8, nbc = (tc + 7) / 8;
    proj_all<<<nbd + nbg + nbc, 512, 0, stream>>>(
        feats_d, feats_g, feats_c, fd, fg, fc, g_d, g_g, g_c,
        nbd, nbg, td, tg, tc);

    long long nthreads = (long long)E * 8;
    gather_kernel<<<(int)((nthreads + 255) / 256), 256, 0, stream>>>(
        g_d, g_g, g_c, i0, i1, ig, ic, out, E);
}